// Round 9
// baseline (181.871 us; speedup 1.0000x reference)
//
#include <hip/hip_runtime.h>
#include <hip/hip_bf16.h>
#include <stdint.h>

// SurrealEmbedding: B=8192, L=618, D=1910
// base[s] = S + sigma*D, S=(p+m)/2, D=(p-m)/2, sigma=+-1.
// hv[b] = P[n_b] + sum_l A_D[b,l] * D_l   (P = fp32 prefix table over S)
// out[b] = hv[b] / ||hv[b]||
#define B_   8192
#define L_   618
#define D_   1910
#define KA   640          // K for the D-GEMM (padded L, multiple of 64)
#define NP   1920         // padded D (multiple of 128)
#define PSTRIDE 1920
#define NCHUNK 40         // 40 chunks x 16 = 640 >= L_

#define ALPHA_F 0.61803400516510009765625f   // float32(1/phi), exact bits

typedef __attribute__((ext_vector_type(8))) short short8;
typedef __attribute__((ext_vector_type(4))) float f32x4;

typedef const __attribute__((address_space(1))) void* gas_ptr;
typedef __attribute__((address_space(3))) void* las_ptr;

__device__ __forceinline__ unsigned short f2bf(float f) {
  union { float f; unsigned u; } v; v.f = f;
  unsigned u = v.u;
  return (unsigned short)((u + 0x7FFFu + ((u >> 16) & 1u)) >> 16);  // RNE
}

// ---------------------------------------------------------------------------
// prep_A: A_D[b][l] = (l<n) ? sigma*w_l : 0   (bf16; w_0=ALPHA, w_{l>=1}=1.0)
// One short8 (16B) store per thread.
// ---------------------------------------------------------------------------
__global__ void prep_A(const int* __restrict__ signs, const int* __restrict__ lengths,
                       unsigned short* __restrict__ A) {
  int id = blockIdx.x * 256 + threadIdx.x;
  int b = id / 80;                // 80 chunks of 8 l's per row
  int chunk = id % 80;
  int l0 = chunk * 8;
  int n = lengths[b];
  const unsigned short w1 = 0x3F80u;          // bf16(1.0)
  const unsigned short wa = f2bf(ALPHA_F);    // bf16(ALPHA)
  short8 v;
#pragma unroll
  for (int e = 0; e < 8; ++e) {
    int l = l0 + e;
    unsigned short val = 0;
    if (l < L_ && l < n) {
      unsigned short w = (l == 0) ? wa : w1;
      int s = signs[b * L_ + l];
      val = s ? (unsigned short)(w | 0x8000u) : w;   // minus -> -w
    }
    v[e] = (short)val;
  }
  *(short8*)(A + (size_t)b * KA + l0) = v;
}

// ---------------------------------------------------------------------------
// prep_B (fused with chunk sums): reads bp/bm once per element.
//  BT[d][l] = bf16((bp-bm)/2)  (transposed via LDS, coalesced both sides)
//  C[c][d]  = sum_{l in chunk c} w_l * (bp+bm)/2   (chunk = 16 l's; the
//             64-l block covers exactly chunks 4*by .. 4*by+3; wt = chunk idx)
// ---------------------------------------------------------------------------
__global__ void prep_B(const float* __restrict__ bp, const float* __restrict__ bm,
                       unsigned short* __restrict__ BT, float* __restrict__ C) {
  __shared__ unsigned short tile[64][65];
  __shared__ float csum[4][4][64];           // [wt][chunk_local][lt]
  int lt = threadIdx.x & 63;
  int wt = threadIdx.x >> 6;       // 0..3
  int l0 = blockIdx.y * 64, d0 = blockIdx.x * 64;
  float cpart[4] = {0.f, 0.f, 0.f, 0.f};
#pragma unroll
  for (int i = 0; i < 16; ++i) {
    int r = i * 4 + wt;            // l-offset within tile
    int l = l0 + r, d = d0 + lt;
    unsigned short v = 0;
    if (l < L_ && d < D_) {
      float a = bp[(size_t)l * D_ + d];
      float b = bm[(size_t)l * D_ + d];
      v = f2bf(0.5f * (a - b));
      float s = 0.5f * (a + b);
      cpart[i >> 2] += (l == 0) ? ALPHA_F * s : s;   // chunk_local = r>>4 = i>>2
    }
    tile[lt][r] = v;               // [d-idx][l-idx]
  }
#pragma unroll
  for (int c = 0; c < 4; ++c) csum[wt][c][lt] = cpart[c];
  __syncthreads();
#pragma unroll
  for (int i = 0; i < 16; ++i) {
    int rd = i * 4 + wt;           // d-offset within tile
    BT[(size_t)(d0 + rd) * KA + l0 + lt] = tile[rd][lt];
  }
  // chunk sum: thread (wt=c, lt=d) reduces over the 4 wt-partials
  int d = d0 + lt;
  if (d < D_) {
    float s = csum[0][wt][lt] + csum[1][wt][lt] + csum[2][wt][lt] + csum[3][wt][lt];
    C[(size_t)(blockIdx.y * 4 + wt) * D_ + d] = s;
  }
}

// ---------------------------------------------------------------------------
// prefix_emit: P[c*16+1+i][d] = sum of chunks < c + running prefix in chunk c.
// ---------------------------------------------------------------------------
__global__ void prefix_emit(const float* __restrict__ bp, const float* __restrict__ bm,
                            const float* __restrict__ C, float* __restrict__ P) {
  int d = blockIdx.x * 256 + threadIdx.x;
  if (d >= D_) return;
  int c = blockIdx.y;
  float off = 0.f;
#pragma unroll
  for (int cc = 0; cc < NCHUNK; ++cc) {
    float v = C[(size_t)cc * D_ + d];
    off += (cc < c) ? v : 0.f;
  }
#pragma unroll
  for (int i = 0; i < 16; ++i) {
    int l = c * 16 + i;
    float v = 0.f;
    if (l < L_) {
      v = 0.5f * (bp[(size_t)l * D_ + d] + bm[(size_t)l * D_ + d]);
      v = (l == 0) ? ALPHA_F * v : v;
    }
    off += v;
    P[(size_t)(l + 1) * PSTRIDE + d] = off;
  }
}

// ---------------------------------------------------------------------------
// GEMM + fused epilogue: C[b][col] = (A_D * D)[b][col] + P[len[b]][col],
// stored unnormalized; per-row sumsq accumulated into SS via atomicAdd.
// 128x128 tile, BK=64, 4 waves of 64x64, 16x16x32 bf16 MFMA,
// global_load_lds width-16 staging (linear LDS dest, pre-swizzled source).
// ---------------------------------------------------------------------------
__global__ __launch_bounds__(256)
void gemm_kernel(const unsigned short* __restrict__ A2,
                 const unsigned short* __restrict__ BT,
                 const int* __restrict__ lengths,
                 const float* __restrict__ P,
                 float* __restrict__ SS,
                 float* __restrict__ out) {
  __shared__ __align__(16) short As[128 * 64];
  __shared__ __align__(16) short Bs[128 * 64];

  const int tid = threadIdx.x;
  const int l   = tid & 63;
  const int w   = tid >> 6;
  const int wm  = w >> 1, wn = w & 1;

  // XCD swizzle: 960 blocks, 8 XCDs, 120 per XCD (960 % 8 == 0).
  const int bid  = blockIdx.x;
  const int wgid = (bid & 7) * 120 + (bid >> 3);
  const int m0   = (wgid / 15) * 128;
  const int n0   = (wgid % 15) * 128;

  f32x4 acc[4][4] = {};

  const int NT = KA / 64;
  for (int kt = 0; kt < NT; ++kt) {
    const int k0 = kt * 64;
    __syncthreads();                       // prev compute done reading LDS
#pragma unroll
    for (int i = 0; i < 4; ++i) {
      int idx = (i * 256 + tid) * 8;       // linear short index in 128x64 tile
      int r = idx >> 6;                    // tile row
      int c = (idx & 63) ^ ((r & 7) << 3); // pre-swizzled source col (involution)
      short* ldsA = As + (size_t)(i * 256 + (tid & ~63)) * 8;
      short* ldsB = Bs + (size_t)(i * 256 + (tid & ~63)) * 8;
      __builtin_amdgcn_global_load_lds((gas_ptr)(A2 + (size_t)(m0 + r) * KA + k0 + c),
                                       (las_ptr)ldsA, 16, 0, 0);
      __builtin_amdgcn_global_load_lds((gas_ptr)(BT + (size_t)(n0 + r) * KA + k0 + c),
                                       (las_ptr)ldsB, 16, 0, 0);
    }
    asm volatile("s_waitcnt vmcnt(0)" ::: "memory");
    __syncthreads();                       // tile fully staged

#pragma unroll
    for (int kk = 0; kk < 64; kk += 32) {
      const int cs = kk + ((l >> 4) << 3);        // short col within tile row
      short8 af[4], bf[4];
#pragma unroll
      for (int m = 0; m < 4; ++m) {
        int r = wm * 64 + m * 16 + (l & 15);
        af[m] = *(const short8*)(As + (r * 64 + (cs ^ ((r & 7) << 3))));
      }
#pragma unroll
      for (int n = 0; n < 4; ++n) {
        int r = wn * 64 + n * 16 + (l & 15);
        bf[n] = *(const short8*)(Bs + (r * 64 + (cs ^ ((r & 7) << 3))));
      }
#pragma unroll
      for (int m = 0; m < 4; ++m)
#pragma unroll
        for (int n = 0; n < 4; ++n)
          acc[m][n] = __builtin_amdgcn_mfma_f32_16x16x32_bf16(af[m], bf[n], acc[m][n], 0, 0, 0);
    }
  }

  // fused epilogue: add P[len[row]], store, per-row sumsq -> atomicAdd(SS)
  const int rl = l >> 4, cl = l & 15;
#pragma unroll
  for (int m = 0; m < 4; ++m) {
    int rbase = m0 + wm * 64 + m * 16 + rl * 4;
    int nlen[4];
#pragma unroll
    for (int q = 0; q < 4; ++q) nlen[q] = lengths[rbase + q];
    float ssq[4] = {0.f, 0.f, 0.f, 0.f};
#pragma unroll
    for (int n = 0; n < 4; ++n) {
      int col = n0 + wn * 64 + n * 16 + cl;
      if (col < D_) {
#pragma unroll
        for (int q = 0; q < 4; ++q) {
          float v = acc[m][n][q] + P[(size_t)nlen[q] * PSTRIDE + col];
          out[(size_t)(rbase + q) * D_ + col] = v;
          ssq[q] += v * v;
        }
      }
    }
#pragma unroll
    for (int q = 0; q < 4; ++q) {
      float s = ssq[q];
      s += __shfl_xor(s, 1, 16);
      s += __shfl_xor(s, 2, 16);
      s += __shfl_xor(s, 4, 16);
      s += __shfl_xor(s, 8, 16);
      if (cl == 0) atomicAdd(&SS[rbase + q], s);
    }
  }
}

// ---------------------------------------------------------------------------
// scale: out[b,:] *= 1/sqrt(SS[b])   (norm>0 guard)
// ---------------------------------------------------------------------------
__global__ void scale_kernel(float* __restrict__ out, const float* __restrict__ SS) {
  int b = blockIdx.x;
  float tot = SS[b];
  float inv = (tot > 0.f) ? (1.0f / sqrtf(tot)) : 1.0f;
  float2* row2 = (float2*)(out + (size_t)b * D_);
#pragma unroll
  for (int j = 0; j < 4; ++j) {
    int c = threadIdx.x + j * 256;       // float2 index, 955 per row
    if (c < 955) {
      float2 v = row2[c];
      v.x *= inv; v.y *= inv;
      row2[c] = v;
    }
  }
}

extern "C" void kernel_launch(void* const* d_in, const int* in_sizes, int n_in,
                              void* d_out, int out_size, void* d_ws, size_t ws_size,
                              hipStream_t stream) {
  const int*   signs   = (const int*)d_in[0];
  const int*   lengths = (const int*)d_in[1];
  const float* bp      = (const float*)d_in[2];
  const float* bm      = (const float*)d_in[3];
  float*       out     = (float*)d_out;

  unsigned short* A  = (unsigned short*)d_ws;                 // [8192][640] bf16 = 10.49 MB
  unsigned short* BT = A + (size_t)B_ * KA;                   // [1920][640] bf16 =  2.46 MB
  float*          P  = (float*)(BT + (size_t)NP * KA);        // [656][1920] f32  =  5.04 MB
  float*          C  = P + (size_t)656 * PSTRIDE;             // [40][1910]  f32  =  0.31 MB
  float*          SS = C + (size_t)NCHUNK * D_;               // [8192]      f32  = 32 KB

  hipMemsetAsync(SS, 0, (size_t)B_ * sizeof(float), stream);
  prep_A<<<(B_ * 80) / 256, 256, 0, stream>>>(signs, lengths, A);
  prep_B<<<dim3(NP / 64, KA / 64), 256, 0, stream>>>(bp, bm, BT, C);
  prefix_emit<<<dim3(8, NCHUNK), 256, 0, stream>>>(bp, bm, C, P);
  gemm_kernel<<<960, 256, 0, stream>>>(A, BT, lengths, P, SS, out);
  scale_kernel<<<B_, 256, 0, stream>>>(out, SS);
}

// Round 11
// 179.320 us; speedup vs baseline: 1.0142x; 1.0142x over previous
//
#include <hip/hip_runtime.h>
#include <hip/hip_bf16.h>
#include <stdint.h>

// SurrealEmbedding: B=8192, L=618, D=1910
// base[s] = S + sigma*D, S=(p+m)/2, D=(p-m)/2, sigma=+-1.
// hv[b] = P[n_b] + sum_l A_D[b,l] * D_l   (P = fp32 prefix table over S)
// out[b] = hv[b] / ||hv[b]||
#define B_   8192
#define L_   618
#define D_   1910
#define KA   640          // K for the D-GEMM (padded L, multiple of 64)
#define NP   1920         // padded D (multiple of 128)
#define PSTRIDE 1920
#define NCHUNK 40         // 40 chunks x 16 = 640 >= L_
#define BK   32           // K-step (double-buffered)

#define ALPHA_F 0.61803400516510009765625f   // float32(1/phi), exact bits

typedef __attribute__((ext_vector_type(8))) short short8;
typedef __attribute__((ext_vector_type(4))) float f32x4;

typedef const __attribute__((address_space(1))) void* gas_ptr;
typedef __attribute__((address_space(3))) void* las_ptr;

__device__ __forceinline__ unsigned short f2bf(float f) {
  union { float f; unsigned u; } v; v.f = f;
  unsigned u = v.u;
  return (unsigned short)((u + 0x7FFFu + ((u >> 16) & 1u)) >> 16);  // RNE
}

// ---------------------------------------------------------------------------
// prep_A: A_D[b][l] = (l<n) ? sigma*w_l : 0   (bf16; w_0=ALPHA, w_{l>=1}=1.0)
// ---------------------------------------------------------------------------
__global__ void prep_A(const int* __restrict__ signs, const int* __restrict__ lengths,
                       unsigned short* __restrict__ A) {
  int id = blockIdx.x * 256 + threadIdx.x;
  int b = id / 80;                // 80 chunks of 8 l's per row
  int chunk = id % 80;
  int l0 = chunk * 8;
  int n = lengths[b];
  const unsigned short w1 = 0x3F80u;          // bf16(1.0)
  const unsigned short wa = f2bf(ALPHA_F);    // bf16(ALPHA)
  short8 v;
#pragma unroll
  for (int e = 0; e < 8; ++e) {
    int l = l0 + e;
    unsigned short val = 0;
    if (l < L_ && l < n) {
      unsigned short w = (l == 0) ? wa : w1;
      int s = signs[b * L_ + l];
      val = s ? (unsigned short)(w | 0x8000u) : w;   // minus -> -w
    }
    v[e] = (short)val;
  }
  *(short8*)(A + (size_t)b * KA + l0) = v;
}

// ---------------------------------------------------------------------------
// prep_B (fused chunk sums): BT[d][l] = bf16((bp-bm)/2) transposed via LDS;
// C[c][d] = sum_{l in chunk c} w_l * (bp+bm)/2.
// ---------------------------------------------------------------------------
__global__ void prep_B(const float* __restrict__ bp, const float* __restrict__ bm,
                       unsigned short* __restrict__ BT, float* __restrict__ C) {
  __shared__ unsigned short tile[64][65];
  __shared__ float csum[4][4][64];           // [wt][chunk_local][lt]
  int lt = threadIdx.x & 63;
  int wt = threadIdx.x >> 6;       // 0..3
  int l0 = blockIdx.y * 64, d0 = blockIdx.x * 64;
  float cpart[4] = {0.f, 0.f, 0.f, 0.f};
#pragma unroll
  for (int i = 0; i < 16; ++i) {
    int r = i * 4 + wt;            // l-offset within tile
    int l = l0 + r, d = d0 + lt;
    unsigned short v = 0;
    if (l < L_ && d < D_) {
      float a = bp[(size_t)l * D_ + d];
      float b = bm[(size_t)l * D_ + d];
      v = f2bf(0.5f * (a - b));
      float s = 0.5f * (a + b);
      cpart[i >> 2] += (l == 0) ? ALPHA_F * s : s;
    }
    tile[lt][r] = v;               // [d-idx][l-idx]
  }
#pragma unroll
  for (int c = 0; c < 4; ++c) csum[wt][c][lt] = cpart[c];
  __syncthreads();
#pragma unroll
  for (int i = 0; i < 16; ++i) {
    int rd = i * 4 + wt;           // d-offset within tile
    BT[(size_t)(d0 + rd) * KA + l0 + lt] = tile[rd][lt];
  }
  int d = d0 + lt;
  if (d < D_) {
    float s = csum[0][wt][lt] + csum[1][wt][lt] + csum[2][wt][lt] + csum[3][wt][lt];
    C[(size_t)(blockIdx.y * 4 + wt) * D_ + d] = s;
  }
}

// ---------------------------------------------------------------------------
// prefix_emit: P[c*16+1+i][d] = sum of chunks < c + running prefix in chunk c.
// ---------------------------------------------------------------------------
__global__ void prefix_emit(const float* __restrict__ bp, const float* __restrict__ bm,
                            const float* __restrict__ C, float* __restrict__ P) {
  int d = blockIdx.x * 256 + threadIdx.x;
  if (d >= D_) return;
  int c = blockIdx.y;
  float off = 0.f;
#pragma unroll
  for (int cc = 0; cc < NCHUNK; ++cc) {
    float v = C[(size_t)cc * D_ + d];
    off += (cc < c) ? v : 0.f;
  }
#pragma unroll
  for (int i = 0; i < 16; ++i) {
    int l = c * 16 + i;
    float v = 0.f;
    if (l < L_) {
      v = 0.5f * (bp[(size_t)l * D_ + d] + bm[(size_t)l * D_ + d]);
      v = (l == 0) ? ALPHA_F * v : v;
    }
    off += v;
    P[(size_t)(l + 1) * PSTRIDE + d] = off;
  }
}

// ---------------------------------------------------------------------------
// GEMM: out[8192][1910] = A_D[8192][640] * D[640][1920] (D transposed input).
// 128x128 tile, BK=32 DOUBLE-BUFFERED global_load_lds pipeline with counted
// vmcnt(4) + raw s_barrier (loads for tile t+1 stay in flight across the
// barrier while tile t computes).  LDS swizzle: short_idx ^= ((r>>1)&3)<<3,
// applied identically on the pre-swizzled global source (involution) and the
// ds_read address.  XCD-aware block swizzle (960 blocks, 120/XCD).
// ---------------------------------------------------------------------------
__global__ __launch_bounds__(256)
void gemm_kernel(const unsigned short* __restrict__ A2,
                 const unsigned short* __restrict__ BT,
                 float* __restrict__ out) {
  __shared__ __align__(16) short As0[128 * BK];
  __shared__ __align__(16) short Bs0[128 * BK];
  __shared__ __align__(16) short As1[128 * BK];
  __shared__ __align__(16) short Bs1[128 * BK];

  const int tid = threadIdx.x;
  const int l   = tid & 63;
  const int w   = tid >> 6;
  const int wm  = w >> 1, wn = w & 1;

  const int bid  = blockIdx.x;
  const int wgid = (bid & 7) * 120 + (bid >> 3);
  const int m0   = (wgid / 15) * 128;
  const int n0   = (wgid % 15) * 128;

  f32x4 acc[4][4] = {};

  // stage lane geometry: 4 lanes per 32-short row; c pre-swizzled (involution)
  const int sr = tid >> 2;                         // row for i=0 (0..63)
  const int sc0 = (tid & 3) << 3;

  // ---- prologue: stage tile 0 into buf0
  {
    const int k0 = 0;
#pragma unroll
    for (int i = 0; i < 2; ++i) {
      int r = i * 64 + sr;
      int c = sc0 ^ ((((r >> 1) & 3)) << 3);
      short* la = As0 + (size_t)(i * 256 + (tid & ~63)) * 8;
      short* lb = Bs0 + (size_t)(i * 256 + (tid & ~63)) * 8;
      __builtin_amdgcn_global_load_lds((gas_ptr)(A2 + (size_t)(m0 + r) * KA + k0 + c),
                                       (las_ptr)la, 16, 0, 0);
      __builtin_amdgcn_global_load_lds((gas_ptr)(BT + (size_t)(n0 + r) * KA + k0 + c),
                                       (las_ptr)lb, 16, 0, 0);
    }
  }

  const int NT = KA / BK;                          // 20
  for (int kt = 0; kt < NT; ++kt) {
    short* curA = (kt & 1) ? As1 : As0;
    short* curB = (kt & 1) ? Bs1 : Bs0;
    short* nxtA = (kt & 1) ? As0 : As1;
    short* nxtB = (kt & 1) ? Bs0 : Bs1;

    if (kt + 1 < NT) {                             // stage tile kt+1
      const int k0 = (kt + 1) * BK;
#pragma unroll
      for (int i = 0; i < 2; ++i) {
        int r = i * 64 + sr;
        int c = sc0 ^ ((((r >> 1) & 3)) << 3);
        short* la = nxtA + (size_t)(i * 256 + (tid & ~63)) * 8;
        short* lb = nxtB + (size_t)(i * 256 + (tid & ~63)) * 8;
        __builtin_amdgcn_global_load_lds((gas_ptr)(A2 + (size_t)(m0 + r) * KA + k0 + c),
                                         (las_ptr)la, 16, 0, 0);
        __builtin_amdgcn_global_load_lds((gas_ptr)(BT + (size_t)(n0 + r) * KA + k0 + c),
                                         (las_ptr)lb, 16, 0, 0);
      }
      asm volatile("s_waitcnt vmcnt(4)" ::: "memory");   // tile kt landed; kt+1 in flight
    } else {
      asm volatile("s_waitcnt vmcnt(0)" ::: "memory");   // last tile: drain
    }
    __builtin_amdgcn_s_barrier();                  // all waves' tile-kt parts visible
    __builtin_amdgcn_sched_barrier(0);             // no ds_read hoisted above barrier

    {
      const int cs = (l >> 4) << 3;                // short col slot in 32-wide row
      short8 af[4], bf[4];
#pragma unroll
      for (int m = 0; m < 4; ++m) {
        int r = wm * 64 + m * 16 + (l & 15);
        af[m] = *(const short8*)(curA + r * BK + (cs ^ ((((r >> 1) & 3)) << 3)));
      }
#pragma unroll
      for (int n = 0; n < 4; ++n) {
        int r = wn * 64 + n * 16 + (l & 15);
        bf[n] = *(const short8*)(curB + r * BK + (cs ^ ((((r >> 1) & 3)) << 3)));
      }
#pragma unroll
      for (int m = 0; m < 4; ++m)
#pragma unroll
        for (int n = 0; n < 4; ++n)
          acc[m][n] = __builtin_amdgcn_mfma_f32_16x16x32_bf16(af[m], bf[n], acc[m][n], 0, 0, 0);
    }
    __builtin_amdgcn_s_barrier();                  // done reading cur before overwrite
  }

  // epilogue: C/D layout col = lane&15, row = (lane>>4)*4 + reg
  const int rl = l >> 4, cl = l & 15;
#pragma unroll
  for (int m = 0; m < 4; ++m) {
#pragma unroll
    for (int n = 0; n < 4; ++n) {
      int col = n0 + wn * 64 + n * 16 + cl;
      if (col < D_) {
        int rbase = m0 + wm * 64 + m * 16 + rl * 4;
#pragma unroll
        for (int q = 0; q < 4; ++q)
          out[(size_t)(rbase + q) * D_ + col] = acc[m][n][q];
      }
    }
  }
}

// ---------------------------------------------------------------------------
// normalize: v = gemm_out[b,:] + P[n_b,:];  out = v / max(||v||, guard)
// float2 vectorized (rows 8B-aligned: 1910*4 = 7640).
// ---------------------------------------------------------------------------
__global__ void normalize_kernel(float* __restrict__ out, const int* __restrict__ lengths,
                                 const float* __restrict__ P) {
  __shared__ float red[4];
  int b = blockIdx.x;
  int n = lengths[b];
  float* row = out + (size_t)b * D_;
  const float* prow = P + (size_t)n * PSTRIDE;
  const float2* row2  = (const float2*)row;
  const float2* prow2 = (const float2*)prow;

  float2 v[4];
  float ss = 0.f;
#pragma unroll
  for (int j = 0; j < 4; ++j) {
    int c = threadIdx.x + j * 256;       // float2 index, 955 per row
    float2 a = make_float2(0.f, 0.f);
    if (c < 955) {
      float2 g = row2[c];
      float2 p = prow2[c];
      a.x = g.x + p.x;
      a.y = g.y + p.y;
    }
    v[j] = a;
    ss += a.x * a.x + a.y * a.y;
  }
#pragma unroll
  for (int off = 32; off > 0; off >>= 1)
    ss += __shfl_down(ss, off, 64);
  int lane = threadIdx.x & 63, wv = threadIdx.x >> 6;
  if (lane == 0) red[wv] = ss;
  __syncthreads();
  float tot = red[0] + red[1] + red[2] + red[3];
  float inv = (tot > 0.f) ? (1.0f / sqrtf(tot)) : 1.0f;
#pragma unroll
  for (int j = 0; j < 4; ++j) {
    int c = threadIdx.x + j * 256;
    if (c < 955) {
      float2 o;
      o.x = v[j].x * inv;
      o.y = v[j].y * inv;
      ((float2*)row)[c] = o;
    }
  }
}

extern "C" void kernel_launch(void* const* d_in, const int* in_sizes, int n_in,
                              void* d_out, int out_size, void* d_ws, size_t ws_size,
                              hipStream_t stream) {
  const int*   signs   = (const int*)d_in[0];
  const int*   lengths = (const int*)d_in[1];
  const float* bp      = (const float*)d_in[2];
  const float* bm      = (const float*)d_in[3];
  float*       out     = (float*)d_out;

  unsigned short* A  = (unsigned short*)d_ws;                 // [8192][640] bf16 = 10.49 MB
  unsigned short* BT = A + (size_t)B_ * KA;                   // [1920][640] bf16 =  2.46 MB
  float*          P  = (float*)(BT + (size_t)NP * KA);        // [656][1920] f32  =  5.04 MB
  float*          C  = P + (size_t)656 * PSTRIDE;             // [40][1910]  f32  =  0.31 MB

  prep_A<<<(B_ * 80) / 256, 256, 0, stream>>>(signs, lengths, A);
  prep_B<<<dim3(NP / 64, KA / 64), 256, 0, stream>>>(bp, bm, BT, C);
  prefix_emit<<<dim3(8, NCHUNK), 256, 0, stream>>>(bp, bm, C, P);
  gemm_kernel<<<960, 256, 0, stream>>>(A, BT, out);
  normalize_kernel<<<B_, 256, 0, stream>>>(out, lengths, P);
}

// Round 12
// 173.540 us; speedup vs baseline: 1.0480x; 1.0333x over previous
//
#include <hip/hip_runtime.h>
#include <hip/hip_bf16.h>
#include <stdint.h>

// SurrealEmbedding: B=8192, L=618, D=1910
// base[s] = S + sigma*D, S=(p+m)/2, D=(p-m)/2, sigma=+-1.
// hv[b] = P[n_b] + sum_l A_D[b,l] * D_l   (P = fp32 prefix table over S)
// out[b] = hv[b] / ||hv[b]||
#define B_   8192
#define L_   618
#define D_   1910
#define KA   640          // K for the D-GEMM (padded L, multiple of 64)
#define NP   1920         // padded D (multiple of 128)
#define PSTRIDE 1920
#define NCHUNK 40         // 40 chunks x 16 = 640 >= L_
#define BK   32           // K-step (triple-buffered, depth-2 prefetch)

#define ALPHA_F 0.61803400516510009765625f   // float32(1/phi), exact bits

typedef __attribute__((ext_vector_type(8))) short short8;
typedef __attribute__((ext_vector_type(4))) float f32x4;

typedef const __attribute__((address_space(1))) void* gas_ptr;
typedef __attribute__((address_space(3))) void* las_ptr;

__device__ __forceinline__ unsigned short f2bf(float f) {
  union { float f; unsigned u; } v; v.f = f;
  unsigned u = v.u;
  return (unsigned short)((u + 0x7FFFu + ((u >> 16) & 1u)) >> 16);  // RNE
}

// ---------------------------------------------------------------------------
// prep_A: A_D[b][l] = (l<n) ? sigma*w_l : 0   (bf16; w_0=ALPHA, w_{l>=1}=1.0)
// ---------------------------------------------------------------------------
__global__ void prep_A(const int* __restrict__ signs, const int* __restrict__ lengths,
                       unsigned short* __restrict__ A) {
  int id = blockIdx.x * 256 + threadIdx.x;
  int b = id / 80;                // 80 chunks of 8 l's per row
  int chunk = id % 80;
  int l0 = chunk * 8;
  int n = lengths[b];
  const unsigned short w1 = 0x3F80u;          // bf16(1.0)
  const unsigned short wa = f2bf(ALPHA_F);    // bf16(ALPHA)
  short8 v;
#pragma unroll
  for (int e = 0; e < 8; ++e) {
    int l = l0 + e;
    unsigned short val = 0;
    if (l < L_ && l < n) {
      unsigned short w = (l == 0) ? wa : w1;
      int s = signs[b * L_ + l];
      val = s ? (unsigned short)(w | 0x8000u) : w;   // minus -> -w
    }
    v[e] = (short)val;
  }
  *(short8*)(A + (size_t)b * KA + l0) = v;
}

// ---------------------------------------------------------------------------
// prep_B (fused): BT[d][l] = bf16((bp-bm)/2) transposed via LDS (coalesced
// both sides); Sw[l][d] = w_l*(bp+bm)/2 (fp32, coalesced); C[c][d] = chunk
// sums of Sw (16 l's per chunk).
// ---------------------------------------------------------------------------
__global__ void prep_B(const float* __restrict__ bp, const float* __restrict__ bm,
                       unsigned short* __restrict__ BT, float* __restrict__ Sw,
                       float* __restrict__ C) {
  __shared__ unsigned short tile[64][65];
  __shared__ float csum[4][4][64];           // [wt][chunk_local][lt]
  int lt = threadIdx.x & 63;
  int wt = threadIdx.x >> 6;       // 0..3
  int l0 = blockIdx.y * 64, d0 = blockIdx.x * 64;
  float cpart[4] = {0.f, 0.f, 0.f, 0.f};
#pragma unroll
  for (int i = 0; i < 16; ++i) {
    int r = i * 4 + wt;            // l-offset within tile
    int l = l0 + r, d = d0 + lt;
    unsigned short v = 0;
    if (l < L_ && d < D_) {
      float a = bp[(size_t)l * D_ + d];
      float b = bm[(size_t)l * D_ + d];
      v = f2bf(0.5f * (a - b));
      float s = 0.5f * (a + b);
      float sw = (l == 0) ? ALPHA_F * s : s;
      Sw[(size_t)l * D_ + d] = sw;
      cpart[i >> 2] += sw;
    }
    tile[lt][r] = v;               // [d-idx][l-idx]
  }
#pragma unroll
  for (int c = 0; c < 4; ++c) csum[wt][c][lt] = cpart[c];
  __syncthreads();
#pragma unroll
  for (int i = 0; i < 16; ++i) {
    int rd = i * 4 + wt;           // d-offset within tile
    BT[(size_t)(d0 + rd) * KA + l0 + lt] = tile[rd][lt];
  }
  int d = d0 + lt;
  if (d < D_) {
    float s = csum[0][wt][lt] + csum[1][wt][lt] + csum[2][wt][lt] + csum[3][wt][lt];
    C[(size_t)(blockIdx.y * 4 + wt) * D_ + d] = s;
  }
}

// ---------------------------------------------------------------------------
// prefix_emit: P[c*16+1+i][d] = sum of chunks < c + running prefix within
// chunk c.  Reads Sw (L3-hot 4.9 MB) + C (305 KB) instead of bp/bm (29 MB).
// ---------------------------------------------------------------------------
__global__ void prefix_emit(const float* __restrict__ Sw, const float* __restrict__ C,
                            float* __restrict__ P) {
  int d = blockIdx.x * 256 + threadIdx.x;
  if (d >= D_) return;
  int c = blockIdx.y;
  float off = 0.f;
#pragma unroll
  for (int cc = 0; cc < NCHUNK; ++cc) {
    float v = C[(size_t)cc * D_ + d];
    off += (cc < c) ? v : 0.f;
  }
#pragma unroll
  for (int i = 0; i < 16; ++i) {
    int l = c * 16 + i;
    float v = (l < L_) ? Sw[(size_t)l * D_ + d] : 0.f;
    off += v;
    P[(size_t)(l + 1) * PSTRIDE + d] = off;
  }
}

// ---------------------------------------------------------------------------
// GEMM: out[8192][1910] = A_D[8192][640] * D[640][1920] (D transposed input).
// 128x128 tile, BK=32, TRIPLE-buffered global_load_lds pipeline, depth-2
// prefetch: stage tile kt+2, wait vmcnt(8) (= tile kt landed; kt+1/kt+2 in
// flight).  Loads get ~2 K-steps to cover latency.  LDS swizzle
// short_idx ^= ((r>>1)&3)<<3 on pre-swizzled source + ds_read (involution).
// XCD-aware block swizzle (960 blocks, 120/XCD).
// ---------------------------------------------------------------------------
__global__ __launch_bounds__(256)
void gemm_kernel(const unsigned short* __restrict__ A2,
                 const unsigned short* __restrict__ BT,
                 float* __restrict__ out) {
  __shared__ __align__(16) short As[3][128 * BK];
  __shared__ __align__(16) short Bs[3][128 * BK];

  const int tid = threadIdx.x;
  const int l   = tid & 63;
  const int w   = tid >> 6;
  const int wm  = w >> 1, wn = w & 1;

  const int bid  = blockIdx.x;
  const int wgid = (bid & 7) * 120 + (bid >> 3);
  const int m0   = (wgid / 15) * 128;
  const int n0   = (wgid % 15) * 128;

  f32x4 acc[4][4] = {};

  // stage lane geometry: 4 lanes per 32-short row; col pre-swizzled (involution)
  const int sr  = tid >> 2;                        // row 0..63 (i=0)
  const int sc0 = (tid & 3) << 3;
  const int ldsoff = (tid & ~63) * 8;              // wave-uniform base offset

#define STAGE(dstA, dstB, kk0)                                                      \
  {                                                                                 \
    _Pragma("unroll")                                                               \
    for (int i = 0; i < 2; ++i) {                                                   \
      int r = i * 64 + sr;                                                          \
      int c = sc0 ^ ((((r >> 1) & 3)) << 3);                                        \
      short* la = (dstA) + (size_t)(i * 2048 + ldsoff);                             \
      short* lb = (dstB) + (size_t)(i * 2048 + ldsoff);                             \
      __builtin_amdgcn_global_load_lds((gas_ptr)(A2 + (size_t)(m0 + r) * KA + (kk0) + c), \
                                       (las_ptr)la, 16, 0, 0);                      \
      __builtin_amdgcn_global_load_lds((gas_ptr)(BT + (size_t)(n0 + r) * KA + (kk0) + c), \
                                       (las_ptr)lb, 16, 0, 0);                      \
    }                                                                               \
  }

  // prologue: stage tiles 0 and 1
  STAGE(As[0], Bs[0], 0)
  STAGE(As[1], Bs[1], BK)

  const int NT = KA / BK;                          // 20
  int cur = 0, stg = 2;
  for (int kt = 0; kt < NT; ++kt) {
    if (kt + 2 < NT) {
      STAGE(As[stg], Bs[stg], (kt + 2) * BK)
      asm volatile("s_waitcnt vmcnt(8)" ::: "memory");   // tile kt landed
    } else if (kt + 1 < NT) {
      asm volatile("s_waitcnt vmcnt(4)" ::: "memory");   // tile kt landed
    } else {
      asm volatile("s_waitcnt vmcnt(0)" ::: "memory");   // last tile: drain
    }
    __builtin_amdgcn_s_barrier();                  // tile kt visible to all waves
    __builtin_amdgcn_sched_barrier(0);             // no ds_read hoisted above

    {
      const short* curA = As[cur];
      const short* curB = Bs[cur];
      const int cs = (l >> 4) << 3;                // short col slot in 32-wide row
      short8 af[4], bf[4];
#pragma unroll
      for (int m = 0; m < 4; ++m) {
        int r = wm * 64 + m * 16 + (l & 15);
        af[m] = *(const short8*)(curA + r * BK + (cs ^ ((((r >> 1) & 3)) << 3)));
      }
#pragma unroll
      for (int n = 0; n < 4; ++n) {
        int r = wn * 64 + n * 16 + (l & 15);
        bf[n] = *(const short8*)(curB + r * BK + (cs ^ ((((r >> 1) & 3)) << 3)));
      }
#pragma unroll
      for (int m = 0; m < 4; ++m)
#pragma unroll
        for (int n = 0; n < 4; ++n)
          acc[m][n] = __builtin_amdgcn_mfma_f32_16x16x32_bf16(af[m], bf[n], acc[m][n], 0, 0, 0);
    }
    __builtin_amdgcn_s_barrier();                  // done reading cur before reuse
    cur = (cur == 2) ? 0 : cur + 1;
    stg = (stg == 2) ? 0 : stg + 1;
  }
#undef STAGE

  // epilogue: C/D layout col = lane&15, row = (lane>>4)*4 + reg
  const int rl = l >> 4, cl = l & 15;
#pragma unroll
  for (int m = 0; m < 4; ++m) {
#pragma unroll
    for (int n = 0; n < 4; ++n) {
      int col = n0 + wn * 64 + n * 16 + cl;
      if (col < D_) {
        int rbase = m0 + wm * 64 + m * 16 + rl * 4;
#pragma unroll
        for (int q = 0; q < 4; ++q)
          out[(size_t)(rbase + q) * D_ + col] = acc[m][n][q];
      }
    }
  }
}

// ---------------------------------------------------------------------------
// normalize: v = gemm_out[b,:] + P[n_b,:];  out = v / max(||v||, guard)
// float2 vectorized (rows 8B-aligned: 1910*4 = 7640).
// ---------------------------------------------------------------------------
__global__ void normalize_kernel(float* __restrict__ out, const int* __restrict__ lengths,
                                 const float* __restrict__ P) {
  __shared__ float red[4];
  int b = blockIdx.x;
  int n = lengths[b];
  float* row = out + (size_t)b * D_;
  const float* prow = P + (size_t)n * PSTRIDE;
  const float2* row2  = (const float2*)row;
  const float2* prow2 = (const float2*)prow;

  float2 v[4];
  float ss = 0.f;
#pragma unroll
  for (int j = 0; j < 4; ++j) {
    int c = threadIdx.x + j * 256;       // float2 index, 955 per row
    float2 a = make_float2(0.f, 0.f);
    if (c < 955) {
      float2 g = row2[c];
      float2 p = prow2[c];
      a.x = g.x + p.x;
      a.y = g.y + p.y;
    }
    v[j] = a;
    ss += a.x * a.x + a.y * a.y;
  }
#pragma unroll
  for (int off = 32; off > 0; off >>= 1)
    ss += __shfl_down(ss, off, 64);
  int lane = threadIdx.x & 63, wv = threadIdx.x >> 6;
  if (lane == 0) red[wv] = ss;
  __syncthreads();
  float tot = red[0] + red[1] + red[2] + red[3];
  float inv = (tot > 0.f) ? (1.0f / sqrtf(tot)) : 1.0f;
#pragma unroll
  for (int j = 0; j < 4; ++j) {
    int c = threadIdx.x + j * 256;
    if (c < 955) {
      float2 o;
      o.x = v[j].x * inv;
      o.y = v[j].y * inv;
      ((float2*)row)[c] = o;
    }
  }
}

extern "C" void kernel_launch(void* const* d_in, const int* in_sizes, int n_in,
                              void* d_out, int out_size, void* d_ws, size_t ws_size,
                              hipStream_t stream) {
  const int*   signs   = (const int*)d_in[0];
  const int*   lengths = (const int*)d_in[1];
  const float* bp      = (const float*)d_in[2];
  const float* bm      = (const float*)d_in[3];
  float*       out     = (float*)d_out;

  unsigned short* A  = (unsigned short*)d_ws;                 // [8192][640] bf16 = 10.49 MB
  unsigned short* BT = A + (size_t)B_ * KA;                   // [1920][640] bf16 =  2.46 MB
  float*          P  = (float*)(BT + (size_t)NP * KA);        // [656][1920] f32  =  5.04 MB
  float*          C  = P + (size_t)656 * PSTRIDE;             // [40][1910]  f32  =  0.31 MB
  float*          Sw = C + (size_t)NCHUNK * D_;               // [640][1910] f32  =  4.89 MB

  prep_A<<<(B_ * 80) / 256, 256, 0, stream>>>(signs, lengths, A);
  prep_B<<<dim3(NP / 64, KA / 64), 256, 0, stream>>>(bp, bm, BT, Sw, C);
  prefix_emit<<<dim3(8, NCHUNK), 256, 0, stream>>>(Sw, C, P);
  gemm_kernel<<<960, 256, 0, stream>>>(A, BT, out);
  normalize_kernel<<<B_, 256, 0, stream>>>(out, lengths, P);
}